// Round 4
// baseline (299.476 us; speedup 1.0000x reference)
//
#include <hip/hip_runtime.h>
#include <stdint.h>
#include <stddef.h>

// Problem constants
#define B_N   4096
#define NSENT 64
#define DDIM  768
#define TOPK  5
#define FAN1  4608   // (TOPK+1)*768
#define H1DIM 1024
#define NCLS  4
#define KDIM  4608

typedef __attribute__((ext_vector_type(8))) __bf16 bf16x8;
typedef __attribute__((ext_vector_type(4))) float  f32x4;

__device__ __forceinline__ unsigned short f2bf(float f) {
    unsigned int u = __float_as_uint(f);
    unsigned int r = (u + 0x7fffu + ((u >> 16) & 1u)) >> 16;
    return (unsigned short)r;
}

__device__ __forceinline__ void gl_lds16(const void* g, void* l) {
    __builtin_amdgcn_global_load_lds((__attribute__((address_space(1))) void*)(g),
                                     (__attribute__((address_space(3))) void*)(l),
                                     16, 0, 0);
}

// ---------------------------------------------------------------------------
// Kernel A: per batch row b: sims[n] = <sim_stance[b], sim_body[b,n]> (f32),
// top-5 (desc, ties -> lower index, matching jax.lax.top_k), then gather
// nli_stance + 5 nli_body rows -> xx[b] as bf16 (4608 elems).
// ---------------------------------------------------------------------------
__global__ __launch_bounds__(256) void k_topk_gather(
    const float* __restrict__ sim_stance,
    const float* __restrict__ sim_body,
    const float* __restrict__ nli_stance,
    const float* __restrict__ nli_body,
    unsigned short* __restrict__ xx)
{
    const int b    = blockIdx.x;
    const int tid  = threadIdx.x;
    const int lane = tid & 63;
    const int wave = tid >> 6;
    __shared__ float sims[NSENT];
    __shared__ int   topidx[TOPK];

    // per-lane stance fragment: elements (j*64+lane)*4 .. +3, j = 0..2
    const float4* st4 = (const float4*)(sim_stance + (size_t)b * DDIM);
    const float4  s0 = st4[lane], s1 = st4[64 + lane], s2 = st4[128 + lane];

    const float* bodyb = sim_body + (size_t)b * NSENT * DDIM;
    for (int n = wave; n < NSENT; n += 4) {
        const float4* r4 = (const float4*)(bodyb + (size_t)n * DDIM);
        float4 a = r4[lane], c = r4[64 + lane], e = r4[128 + lane];
        float p = a.x*s0.x + a.y*s0.y + a.z*s0.z + a.w*s0.w
                + c.x*s1.x + c.y*s1.y + c.z*s1.z + c.w*s1.w
                + e.x*s2.x + e.y*s2.y + e.z*s2.z + e.w*s2.w;
        #pragma unroll
        for (int off = 32; off; off >>= 1) p += __shfl_xor(p, off);
        if (lane == 0) sims[n] = p;
    }
    __syncthreads();

    // wave 0: 5x butterfly argmax (strict >, tie -> lower index)
    if (wave == 0) {
        float v = sims[lane];
        #pragma unroll
        for (int k = 0; k < TOPK; ++k) {
            float bv = v; int bi = lane;
            #pragma unroll
            for (int off = 32; off; off >>= 1) {
                float ov = __shfl_xor(bv, off);
                int   oi = __shfl_xor(bi, off);
                if (ov > bv || (ov == bv && oi < bi)) { bv = ov; bi = oi; }
            }
            if (lane == 0) topidx[k] = bi;
            if (lane == bi) v = -3.402823466e38f;
        }
    }
    __syncthreads();

    // gather + f32->bf16 convert: 6 segments of 768 floats (192 float4 each)
    unsigned short* xrow = xx + (size_t)b * FAN1;
    for (int task = tid; task < 1152; task += 256) {
        const int seg = task / 192;
        const int t   = task - seg * 192;
        const float* src = (seg == 0)
            ? (nli_stance + (size_t)b * DDIM)
            : (nli_body + ((size_t)b * NSENT + topidx[seg - 1]) * DDIM);
        float4 v = ((const float4*)src)[t];
        ushort4 o;
        o.x = f2bf(v.x); o.y = f2bf(v.y); o.z = f2bf(v.z); o.w = f2bf(v.w);
        ((ushort4*)(xrow + seg * DDIM))[t] = o;
    }
}

// ---------------------------------------------------------------------------
// W1 f32 -> bf16 (row-major [H1][FAN1] preserved; acts as B^T for the GEMM)
// ---------------------------------------------------------------------------
__global__ __launch_bounds__(256) void k_f32_to_bf16x4(
    const float* __restrict__ in, unsigned short* __restrict__ o, int n4)
{
    int i = blockIdx.x * 256 + threadIdx.x;
    if (i < n4) {
        float4 v = ((const float4*)in)[i];
        ushort4 r;
        r.x = f2bf(v.x); r.y = f2bf(v.y); r.z = f2bf(v.z); r.w = f2bf(v.w);
        ((ushort4*)o)[i] = r;
    }
}

// ---------------------------------------------------------------------------
// GEMM1: hidden[m][h] = relu( sum_k xx[m][k]*W1[h][k] + b1[h] )
// M=4096 N=1024 K=4608, bf16 MFMA 16x16x32.
// BM=128 BN=64 BK=64, 4 waves (2m x 2n), wave tile 64x32.
// 2-phase prefetch pipeline (T3 minimum recipe): double-buffered LDS;
// issue next tile's global_load_lds BEFORE computing current tile; single
// __syncthreads per K-step drains the prefetch after compute ran under it.
// Buffer parity is compile-time (x2 unroll) so gl_lds writes and ds_reads
// target provably-disjoint LDS regions.
// LDS chunk swizzle (both-sides involution): chunk slot c of row r holds
// global chunk (c ^ (r&7)); gl_lds dest linear, per-lane GLOBAL source
// permuted; fragment reads apply same XOR -> 2-way conflicts only (free).
// ---------------------------------------------------------------------------
__global__ __launch_bounds__(256, 2) void k_gemm1(
    const unsigned short* __restrict__ A,   // xx bf16 [4096][4608]
    const unsigned short* __restrict__ W,   // W1 bf16 [1024][4608]
    const float* __restrict__ bias,
    float* __restrict__ Hd)                 // [4096][1024] f32
{
    constexpr int BM = 128, BN = 64, BK = 64;
    constexpr int K = KDIM;                 // 72 K-tiles
    __shared__ unsigned short lA[2][BM * BK];  // 2 x 16 KB
    __shared__ unsigned short lB[2][BN * BK];  // 2 x 8 KB

    const int tid = threadIdx.x, lane = tid & 63, wave = tid >> 6;
    const int bn = blockIdx.x & 15, bm = blockIdx.x >> 4;
    const int wm = wave >> 1, wn = wave & 1;

    // ---- staging setup ----
    const int q   = wave * 64 + lane;
    const int q8  = q >> 3;              // row within 32-row group
    const int sc  = (q & 7) ^ (q8 & 7);  // swizzled global chunk-in-row
    const unsigned short* gA[4];
    const unsigned short* gB[2];
    #pragma unroll
    for (int j = 0; j < 4; ++j)
        gA[j] = A + (size_t)(bm * BM + j * 32 + q8) * K + sc * 8;
    #pragma unroll
    for (int j = 0; j < 2; ++j)
        gB[j] = W + (size_t)(bn * BN + j * 32 + q8) * K + sc * 8;
    const int ldsOff = (wave * 64) * 8;   // wave-uniform dest offset in chunks*8

    // ---- fragment read setup (swizzled) ----
    const int r16 = lane & 15;
    const int p0  = (lane >> 4) ^ (r16 & 7);   // chunk slot for k-half 0
    const int p1  = p0 ^ 4;                    // chunk slot for k-half 1
    const int aRowOff = (wm * 64 + r16) * BK;
    const int bRowOff = (wn * 32 + r16) * BK;

    f32x4 acc[4][2];
    #pragma unroll
    for (int m = 0; m < 4; ++m)
        #pragma unroll
        for (int n = 0; n < 2; ++n) acc[m][n] = {0.f, 0.f, 0.f, 0.f};

#define STAGE(SEL) do {                                                     \
    _Pragma("unroll")                                                       \
    for (int j = 0; j < 4; ++j) {                                           \
        gl_lds16(gA[j], &lA[SEL][j * 2048 + ldsOff]); gA[j] += BK;          \
    }                                                                       \
    _Pragma("unroll")                                                       \
    for (int j = 0; j < 2; ++j) {                                           \
        gl_lds16(gB[j], &lB[SEL][j * 2048 + ldsOff]); gB[j] += BK;          \
    }                                                                       \
} while (0)

#define COMPUTE(SEL) do {                                                   \
    bf16x8 fa[4][2], fb[2][2];                                              \
    _Pragma("unroll")                                                       \
    for (int m = 0; m < 4; ++m) {                                           \
        fa[m][0] = *(const bf16x8*)(&lA[SEL][aRowOff + m * 16 * BK + p0 * 8]); \
        fa[m][1] = *(const bf16x8*)(&lA[SEL][aRowOff + m * 16 * BK + p1 * 8]); \
    }                                                                       \
    _Pragma("unroll")                                                       \
    for (int n = 0; n < 2; ++n) {                                           \
        fb[n][0] = *(const bf16x8*)(&lB[SEL][bRowOff + n * 16 * BK + p0 * 8]); \
        fb[n][1] = *(const bf16x8*)(&lB[SEL][bRowOff + n * 16 * BK + p1 * 8]); \
    }                                                                       \
    _Pragma("unroll")                                                       \
    for (int h = 0; h < 2; ++h)                                             \
        _Pragma("unroll")                                                   \
        for (int m = 0; m < 4; ++m)                                         \
            _Pragma("unroll")                                               \
            for (int n = 0; n < 2; ++n)                                     \
                acc[m][n] = __builtin_amdgcn_mfma_f32_16x16x32_bf16(        \
                    fa[m][h], fb[n][h], acc[m][n], 0, 0, 0);                \
} while (0)

    // tiles 0..71; prologue stages tile 0
    STAGE(0);
    __syncthreads();
    #pragma unroll 1
    for (int it = 0; it < 35; ++it) {
        STAGE(1); COMPUTE(0); __syncthreads();   // stage 2it+1, compute 2it
        STAGE(0); COMPUTE(1); __syncthreads();   // stage 2it+2, compute 2it+1
    }
    STAGE(1); COMPUTE(0); __syncthreads();       // stage 71, compute 70
    COMPUTE(1);                                  // compute 71

#undef STAGE
#undef COMPUTE

    // epilogue: C/D layout col=lane&15, row=(lane>>4)*4+reg
    const int colbase = bn * BN + wn * 32 + r16;
    const int rowbase = bm * BM + wm * 64 + (lane >> 4) * 4;
    #pragma unroll
    for (int n = 0; n < 2; ++n) {
        const int col = colbase + n * 16;
        const float bv = bias[col];
        #pragma unroll
        for (int m = 0; m < 4; ++m) {
            const int row = rowbase + m * 16;
            #pragma unroll
            for (int j = 0; j < 4; ++j) {
                float v = acc[m][n][j] + bv;
                Hd[(size_t)(row + j) * H1DIM + col] = v > 0.f ? v : 0.f;
            }
        }
    }
}

// ---------------------------------------------------------------------------
// GEMM2: out[b][c] = sum_h hidden[b][h]*W2[c][h] + b2[c]; one wave per row.
// ---------------------------------------------------------------------------
__global__ __launch_bounds__(256) void k_gemm2(
    const float* __restrict__ Hd, const float* __restrict__ W2,
    const float* __restrict__ b2, float* __restrict__ out)
{
    __shared__ float w2s[NCLS * H1DIM];
    const int tid = threadIdx.x, lane = tid & 63, wave = tid >> 6;
    const int row = blockIdx.x * 4 + wave;
    for (int i = tid; i < NCLS * H1DIM; i += 256) w2s[i] = W2[i];
    __syncthreads();

    const float4* h4 = (const float4*)(Hd + (size_t)row * H1DIM);
    const float4* w0 = (const float4*)&w2s[0];
    const float4* w1 = (const float4*)&w2s[H1DIM];
    const float4* w2 = (const float4*)&w2s[2 * H1DIM];
    const float4* w3 = (const float4*)&w2s[3 * H1DIM];
    float a0 = 0.f, a1 = 0.f, a2 = 0.f, a3 = 0.f;
    #pragma unroll
    for (int j = 0; j < 4; ++j) {
        const int idx = j * 64 + lane;
        float4 h = h4[idx], xv;
        xv = w0[idx]; a0 += h.x*xv.x + h.y*xv.y + h.z*xv.z + h.w*xv.w;
        xv = w1[idx]; a1 += h.x*xv.x + h.y*xv.y + h.z*xv.z + h.w*xv.w;
        xv = w2[idx]; a2 += h.x*xv.x + h.y*xv.y + h.z*xv.z + h.w*xv.w;
        xv = w3[idx]; a3 += h.x*xv.x + h.y*xv.y + h.z*xv.z + h.w*xv.w;
    }
    #pragma unroll
    for (int off = 32; off; off >>= 1) {
        a0 += __shfl_xor(a0, off);
        a1 += __shfl_xor(a1, off);
        a2 += __shfl_xor(a2, off);
        a3 += __shfl_xor(a3, off);
    }
    if (lane == 0) {
        float* o = out + (size_t)row * NCLS;
        o[0] = a0 + b2[0]; o[1] = a1 + b2[1]; o[2] = a2 + b2[2]; o[3] = a3 + b2[3];
    }
}

// ---------------------------------------------------------------------------
// Workspace layout (bytes):
//   [0, 37748736)                 xx bf16      4096*4608*2
//   [37748736, 47185920)          W1 bf16      1024*4608*2
//   [47185920, 63963136)          hidden f32   4096*1024*4
// ---------------------------------------------------------------------------
extern "C" void kernel_launch(void* const* d_in, const int* in_sizes, int n_in,
                              void* d_out, int out_size, void* d_ws, size_t ws_size,
                              hipStream_t stream)
{
    const float* sim_stance = (const float*)d_in[0];
    const float* nli_stance = (const float*)d_in[1];
    const float* sim_body   = (const float*)d_in[2];
    const float* nli_body   = (const float*)d_in[3];
    const float* W1 = (const float*)d_in[4];
    const float* b1 = (const float*)d_in[5];
    const float* W2 = (const float*)d_in[6];
    const float* b2 = (const float*)d_in[7];
    float* out = (float*)d_out;

    char* ws = (char*)d_ws;
    unsigned short* xx     = (unsigned short*)ws;
    unsigned short* w1b    = (unsigned short*)(ws + 37748736u);
    float*          hidden = (float*)(ws + 37748736u + 9437184u);

    k_f32_to_bf16x4<<<dim3(4608), dim3(256), 0, stream>>>(W1, w1b, 1179648);
    k_topk_gather<<<dim3(B_N), dim3(256), 0, stream>>>(sim_stance, sim_body,
                                                       nli_stance, nli_body, xx);
    k_gemm1<<<dim3(512), dim3(256), 0, stream>>>(xx, w1b, b1, hidden);
    k_gemm2<<<dim3(1024), dim3(256), 0, stream>>>(hidden, W2, b2, out);
}

// Round 5
// 274.517 us; speedup vs baseline: 1.0909x; 1.0909x over previous
//
#include <hip/hip_runtime.h>
#include <stdint.h>
#include <stddef.h>

// Problem constants
#define B_N   4096
#define NSENT 64
#define DDIM  768
#define TOPK  5
#define FAN1  4608   // (TOPK+1)*768
#define H1DIM 1024
#define NCLS  4
#define KDIM  4608

typedef __attribute__((ext_vector_type(8))) __bf16 bf16x8;
typedef __attribute__((ext_vector_type(4))) float  f32x4;

__device__ __forceinline__ unsigned short f2bf(float f) {
    unsigned int u = __float_as_uint(f);
    unsigned int r = (u + 0x7fffu + ((u >> 16) & 1u)) >> 16;
    return (unsigned short)r;
}

__device__ __forceinline__ void gl_lds16(const void* g, void* l) {
    __builtin_amdgcn_global_load_lds((__attribute__((address_space(1))) void*)(g),
                                     (__attribute__((address_space(3))) void*)(l),
                                     16, 0, 0);
}

// ---------------------------------------------------------------------------
// Kernel A: per batch row b: sims[n] = <sim_stance[b], sim_body[b,n]> (f32),
// top-5 (strict >, tie -> lower index, matching jax.lax.top_k), then gather
// nli_stance + 5 nli_body rows -> xx[b] as bf16 (4608 elems).
// Dot layout: each wave handles 16 rows, 4 rows per iteration; 16-lane
// column slices (lane&15 -> float4 indices c, c+16, ..., c+176) so the
// cross-lane reduce is 4 shfl steps for 4 rows (1 shfl/row vs 6 before).
// ---------------------------------------------------------------------------
__global__ __launch_bounds__(256) void k_topk_gather(
    const float* __restrict__ sim_stance,
    const float* __restrict__ sim_body,
    const float* __restrict__ nli_stance,
    const float* __restrict__ nli_body,
    unsigned short* __restrict__ xx)
{
    const int b    = blockIdx.x;
    const int tid  = threadIdx.x;
    const int lane = tid & 63;
    const int wave = tid >> 6;
    const int g    = lane >> 4;     // row-group 0..3
    const int c    = lane & 15;     // column slice
    __shared__ float sims[NSENT];
    __shared__ int   topidx[TOPK];

    // stance slice: float4 indices c + 16*j, j = 0..11 (48 floats/lane)
    const float4* st4 = (const float4*)(sim_stance + (size_t)b * DDIM);
    float4 st[12];
    #pragma unroll
    for (int j = 0; j < 12; ++j) st[j] = st4[c + 16 * j];

    const float* bodyb = sim_body + (size_t)b * NSENT * DDIM;
    #pragma unroll 1
    for (int it = 0; it < 4; ++it) {
        const int r = wave * 16 + it * 4 + g;
        const float4* r4 = (const float4*)(bodyb + (size_t)r * DDIM);
        float p = 0.f;
        #pragma unroll
        for (int j = 0; j < 12; ++j) {
            float4 v = r4[c + 16 * j];
            p += v.x*st[j].x + v.y*st[j].y + v.z*st[j].z + v.w*st[j].w;
        }
        // reduce across the 16-lane group
        #pragma unroll
        for (int off = 8; off; off >>= 1) p += __shfl_xor(p, off);
        if (c == 0) sims[r] = p;
    }
    __syncthreads();

    // wave 0: 5x butterfly argmax (strict >, tie -> lower index)
    if (wave == 0) {
        float v = sims[lane];
        #pragma unroll
        for (int k = 0; k < TOPK; ++k) {
            float bv = v; int bi = lane;
            #pragma unroll
            for (int off = 32; off; off >>= 1) {
                float ov = __shfl_xor(bv, off);
                int   oi = __shfl_xor(bi, off);
                if (ov > bv || (ov == bv && oi < bi)) { bv = ov; bi = oi; }
            }
            if (lane == 0) topidx[k] = bi;
            if (lane == bi) v = -3.402823466e38f;
        }
    }
    __syncthreads();

    // gather + f32->bf16 convert: 6 segments of 768 floats (192 float4 each)
    unsigned short* xrow = xx + (size_t)b * FAN1;
    for (int task = tid; task < 1152; task += 256) {
        const int seg = task / 192;
        const int t   = task - seg * 192;
        const float* src = (seg == 0)
            ? (nli_stance + (size_t)b * DDIM)
            : (nli_body + ((size_t)b * NSENT + topidx[seg - 1]) * DDIM);
        float4 v = ((const float4*)src)[t];
        ushort4 o;
        o.x = f2bf(v.x); o.y = f2bf(v.y); o.z = f2bf(v.z); o.w = f2bf(v.w);
        ((ushort4*)(xrow + seg * DDIM))[t] = o;
    }
}

// ---------------------------------------------------------------------------
// W1 f32 -> bf16 (row-major [H1][FAN1] preserved; acts as B^T for the GEMM)
// ---------------------------------------------------------------------------
__global__ __launch_bounds__(256) void k_f32_to_bf16x4(
    const float* __restrict__ in, unsigned short* __restrict__ o, int n4)
{
    int i = blockIdx.x * 256 + threadIdx.x;
    if (i < n4) {
        float4 v = ((const float4*)in)[i];
        ushort4 r;
        r.x = f2bf(v.x); r.y = f2bf(v.y); r.z = f2bf(v.z); r.w = f2bf(v.w);
        ((ushort4*)o)[i] = r;
    }
}

// ---------------------------------------------------------------------------
// GEMM1: hidden[m][h] = relu( sum_k xx[m][k]*W1[h][k] + b1[h] )
// M=4096 N=1024 K=4608, bf16 MFMA 16x16x32.
// BM=128 BN=64 BK=64, 4 waves (2m x 2n), wave tile 64x32 (R3 structure —
// measured best). NEW: T1 XCD-aware swizzle — HW assigns XCD = bid % 8;
// work id wk = (bid&7)*64 + (bid>>3) gives each XCD 64 consecutive work
// items = 4 bm-rows x all 16 bn -> per-XCD A working set 4.7 MB (mostly
// L2-resident) instead of ~27 bm rows (32 MB, L2 thrash -> L3-BW-bound).
// LDS chunk swizzle (both-sides involution): chunk slot cc of row r holds
// global chunk (cc ^ (r&7)); gl_lds dest linear, per-lane GLOBAL source
// permuted; fragment reads apply same XOR -> 2-way conflicts only (free).
// ---------------------------------------------------------------------------
__global__ __launch_bounds__(256, 2) void k_gemm1(
    const unsigned short* __restrict__ A,   // xx bf16 [4096][4608]
    const unsigned short* __restrict__ W,   // W1 bf16 [1024][4608]
    const float* __restrict__ bias,
    float* __restrict__ Hd)                 // [4096][1024] f32
{
    constexpr int BM = 128, BN = 64, BK = 64;
    constexpr int K = KDIM;
    __shared__ unsigned short lA[BM * BK];  // 16 KB
    __shared__ unsigned short lB[BN * BK];  // 8 KB

    const int tid = threadIdx.x, lane = tid & 63, wave = tid >> 6;
    const int bid = blockIdx.x;
    const int wk  = (bid & 7) * 64 + (bid >> 3);   // XCD-grouped work id
    const int bn  = wk & 15, bm = wk >> 4;
    const int wm = wave >> 1, wn = wave & 1;

    // ---- staging setup ----
    const int q   = wave * 64 + lane;
    const int q8  = q >> 3;              // row within 32-row group
    const int sc  = (q & 7) ^ (q8 & 7);  // swizzled global chunk-in-row
    const unsigned short* gA[4];
    const unsigned short* gB[2];
    #pragma unroll
    for (int j = 0; j < 4; ++j)
        gA[j] = A + (size_t)(bm * BM + j * 32 + q8) * K + sc * 8;
    #pragma unroll
    for (int j = 0; j < 2; ++j)
        gB[j] = W + (size_t)(bn * BN + j * 32 + q8) * K + sc * 8;
    unsigned short* lAd[4];
    unsigned short* lBd[2];
    #pragma unroll
    for (int j = 0; j < 4; ++j) lAd[j] = &lA[(j * 256 + wave * 64) * 8];
    #pragma unroll
    for (int j = 0; j < 2; ++j) lBd[j] = &lB[(j * 256 + wave * 64) * 8];

    // ---- fragment read setup (swizzled) ----
    const int r16 = lane & 15;
    const int p0  = (lane >> 4) ^ (r16 & 7);   // chunk slot for k-half 0
    const int p1  = p0 ^ 4;                    // chunk slot for k-half 1
    const unsigned short* paBase = &lA[(wm * 64 + r16) * BK];
    const unsigned short* pbBase = &lB[(wn * 32 + r16) * BK];

    f32x4 acc[4][2];
    #pragma unroll
    for (int m = 0; m < 4; ++m)
        #pragma unroll
        for (int n = 0; n < 2; ++n) acc[m][n] = {0.f, 0.f, 0.f, 0.f};

    for (int kt = 0; kt < K / BK; ++kt) {
        #pragma unroll
        for (int j = 0; j < 4; ++j) { gl_lds16(gA[j], lAd[j]); gA[j] += BK; }
        #pragma unroll
        for (int j = 0; j < 2; ++j) { gl_lds16(gB[j], lBd[j]); gB[j] += BK; }
        __syncthreads();   // compiler emits vmcnt(0) drain before barrier

        bf16x8 fa[4][2], fb[2][2];
        #pragma unroll
        for (int m = 0; m < 4; ++m) {
            fa[m][0] = *(const bf16x8*)(paBase + m * 16 * BK + p0 * 8);
            fa[m][1] = *(const bf16x8*)(paBase + m * 16 * BK + p1 * 8);
        }
        #pragma unroll
        for (int n = 0; n < 2; ++n) {
            fb[n][0] = *(const bf16x8*)(pbBase + n * 16 * BK + p0 * 8);
            fb[n][1] = *(const bf16x8*)(pbBase + n * 16 * BK + p1 * 8);
        }
        #pragma unroll
        for (int h = 0; h < 2; ++h)
            #pragma unroll
            for (int m = 0; m < 4; ++m)
                #pragma unroll
                for (int n = 0; n < 2; ++n)
                    acc[m][n] = __builtin_amdgcn_mfma_f32_16x16x32_bf16(
                        fa[m][h], fb[n][h], acc[m][n], 0, 0, 0);
        __syncthreads();
    }

    // epilogue: C/D layout col=lane&15, row=(lane>>4)*4+reg
    const int colbase = bn * BN + wn * 32 + r16;
    const int rowbase = bm * BM + wm * 64 + (lane >> 4) * 4;
    #pragma unroll
    for (int n = 0; n < 2; ++n) {
        const int col = colbase + n * 16;
        const float bv = bias[col];
        #pragma unroll
        for (int m = 0; m < 4; ++m) {
            const int row = rowbase + m * 16;
            #pragma unroll
            for (int j = 0; j < 4; ++j) {
                float v = acc[m][n][j] + bv;
                Hd[(size_t)(row + j) * H1DIM + col] = v > 0.f ? v : 0.f;
            }
        }
    }
}

// ---------------------------------------------------------------------------
// GEMM2: out[b][c] = sum_h hidden[b][h]*W2[c][h] + b2[c]; one wave per row.
// ---------------------------------------------------------------------------
__global__ __launch_bounds__(256) void k_gemm2(
    const float* __restrict__ Hd, const float* __restrict__ W2,
    const float* __restrict__ b2, float* __restrict__ out)
{
    __shared__ float w2s[NCLS * H1DIM];
    const int tid = threadIdx.x, lane = tid & 63, wave = tid >> 6;
    const int row = blockIdx.x * 4 + wave;
    for (int i = tid; i < NCLS * H1DIM; i += 256) w2s[i] = W2[i];
    __syncthreads();

    const float4* h4 = (const float4*)(Hd + (size_t)row * H1DIM);
    const float4* w0 = (const float4*)&w2s[0];
    const float4* w1 = (const float4*)&w2s[H1DIM];
    const float4* w2 = (const float4*)&w2s[2 * H1DIM];
    const float4* w3 = (const float4*)&w2s[3 * H1DIM];
    float a0 = 0.f, a1 = 0.f, a2 = 0.f, a3 = 0.f;
    #pragma unroll
    for (int j = 0; j < 4; ++j) {
        const int idx = j * 64 + lane;
        float4 h = h4[idx], xv;
        xv = w0[idx]; a0 += h.x*xv.x + h.y*xv.y + h.z*xv.z + h.w*xv.w;
        xv = w1[idx]; a1 += h.x*xv.x + h.y*xv.y + h.z*xv.z + h.w*xv.w;
        xv = w2[idx]; a2 += h.x*xv.x + h.y*xv.y + h.z*xv.z + h.w*xv.w;
        xv = w3[idx]; a3 += h.x*xv.x + h.y*xv.y + h.z*xv.z + h.w*xv.w;
    }
    #pragma unroll
    for (int off = 32; off; off >>= 1) {
        a0 += __shfl_xor(a0, off);
        a1 += __shfl_xor(a1, off);
        a2 += __shfl_xor(a2, off);
        a3 += __shfl_xor(a3, off);
    }
    if (lane == 0) {
        float* o = out + (size_t)row * NCLS;
        o[0] = a0 + b2[0]; o[1] = a1 + b2[1]; o[2] = a2 + b2[2]; o[3] = a3 + b2[3];
    }
}

// ---------------------------------------------------------------------------
// Workspace layout (bytes):
//   [0, 37748736)                 xx bf16      4096*4608*2
//   [37748736, 47185920)          W1 bf16      1024*4608*2
//   [47185920, 63963136)          hidden f32   4096*1024*4
// ---------------------------------------------------------------------------
extern "C" void kernel_launch(void* const* d_in, const int* in_sizes, int n_in,
                              void* d_out, int out_size, void* d_ws, size_t ws_size,
                              hipStream_t stream)
{
    const float* sim_stance = (const float*)d_in[0];
    const float* nli_stance = (const float*)d_in[1];
    const float* sim_body   = (const float*)d_in[2];
    const float* nli_body   = (const float*)d_in[3];
    const float* W1 = (const float*)d_in[4];
    const float* b1 = (const float*)d_in[5];
    const float* W2 = (const float*)d_in[6];
    const float* b2 = (const float*)d_in[7];
    float* out = (float*)d_out;

    char* ws = (char*)d_ws;
    unsigned short* xx     = (unsigned short*)ws;
    unsigned short* w1b    = (unsigned short*)(ws + 37748736u);
    float*          hidden = (float*)(ws + 37748736u + 9437184u);

    k_f32_to_bf16x4<<<dim3(4608), dim3(256), 0, stream>>>(W1, w1b, 1179648);
    k_topk_gather<<<dim3(B_N), dim3(256), 0, stream>>>(sim_stance, sim_body,
                                                       nli_stance, nli_body, xx);
    k_gemm1<<<dim3(512), dim3(256), 0, stream>>>(xx, w1b, b1, hidden);
    k_gemm2<<<dim3(1024), dim3(256), 0, stream>>>(hidden, W2, b2, out);
}

// Round 6
// 255.016 us; speedup vs baseline: 1.1743x; 1.0765x over previous
//
#include <hip/hip_runtime.h>
#include <stdint.h>
#include <stddef.h>

// Problem constants
#define B_N   4096
#define NSENT 64
#define DDIM  768
#define TOPK  5
#define FAN1  4608   // (TOPK+1)*768
#define H1DIM 1024
#define NCLS  4
#define KDIM  4608
#define KHALF 2304   // split-K: K per block

typedef __attribute__((ext_vector_type(8))) __bf16 bf16x8;
typedef __attribute__((ext_vector_type(4))) float  f32x4;

__device__ __forceinline__ unsigned short f2bf(float f) {
    unsigned int u = __float_as_uint(f);
    unsigned int r = (u + 0x7fffu + ((u >> 16) & 1u)) >> 16;
    return (unsigned short)r;
}

__device__ __forceinline__ void gl_lds16(const void* g, void* l) {
    __builtin_amdgcn_global_load_lds((__attribute__((address_space(1))) void*)(g),
                                     (__attribute__((address_space(3))) void*)(l),
                                     16, 0, 0);
}

// ---------------------------------------------------------------------------
// Kernel A: per batch row b: sims[n] = <sim_stance[b], sim_body[b,n]> (f32),
// top-5 (strict >, tie -> lower index, matching jax.lax.top_k), then gather
// nli_stance + 5 nli_body rows -> xx[b] as bf16 (4608 elems).
// ---------------------------------------------------------------------------
__global__ __launch_bounds__(256) void k_topk_gather(
    const float* __restrict__ sim_stance,
    const float* __restrict__ sim_body,
    const float* __restrict__ nli_stance,
    const float* __restrict__ nli_body,
    unsigned short* __restrict__ xx)
{
    const int b    = blockIdx.x;
    const int tid  = threadIdx.x;
    const int lane = tid & 63;
    const int wave = tid >> 6;
    const int g    = lane >> 4;     // row-group 0..3
    const int c    = lane & 15;     // column slice
    __shared__ float sims[NSENT];
    __shared__ int   topidx[TOPK];

    // stance slice: float4 indices c + 16*j, j = 0..11 (48 floats/lane)
    const float4* st4 = (const float4*)(sim_stance + (size_t)b * DDIM);
    float4 st[12];
    #pragma unroll
    for (int j = 0; j < 12; ++j) st[j] = st4[c + 16 * j];

    const float* bodyb = sim_body + (size_t)b * NSENT * DDIM;
    #pragma unroll 1
    for (int it = 0; it < 4; ++it) {
        const int r = wave * 16 + it * 4 + g;
        const float4* r4 = (const float4*)(bodyb + (size_t)r * DDIM);
        float p = 0.f;
        #pragma unroll
        for (int j = 0; j < 12; ++j) {
            float4 v = r4[c + 16 * j];
            p += v.x*st[j].x + v.y*st[j].y + v.z*st[j].z + v.w*st[j].w;
        }
        #pragma unroll
        for (int off = 8; off; off >>= 1) p += __shfl_xor(p, off);
        if (c == 0) sims[r] = p;
    }
    __syncthreads();

    // wave 0: 5x butterfly argmax (strict >, tie -> lower index)
    if (wave == 0) {
        float v = sims[lane];
        #pragma unroll
        for (int k = 0; k < TOPK; ++k) {
            float bv = v; int bi = lane;
            #pragma unroll
            for (int off = 32; off; off >>= 1) {
                float ov = __shfl_xor(bv, off);
                int   oi = __shfl_xor(bi, off);
                if (ov > bv || (ov == bv && oi < bi)) { bv = ov; bi = oi; }
            }
            if (lane == 0) topidx[k] = bi;
            if (lane == bi) v = -3.402823466e38f;
        }
    }
    __syncthreads();

    // gather + f32->bf16 convert: 6 segments of 768 floats (192 float4 each)
    unsigned short* xrow = xx + (size_t)b * FAN1;
    for (int task = tid; task < 1152; task += 256) {
        const int seg = task / 192;
        const int t   = task - seg * 192;
        const float* src = (seg == 0)
            ? (nli_stance + (size_t)b * DDIM)
            : (nli_body + ((size_t)b * NSENT + topidx[seg - 1]) * DDIM);
        float4 v = ((const float4*)src)[t];
        ushort4 o;
        o.x = f2bf(v.x); o.y = f2bf(v.y); o.z = f2bf(v.z); o.w = f2bf(v.w);
        ((ushort4*)(xrow + seg * DDIM))[t] = o;
    }
}

// ---------------------------------------------------------------------------
// W1 f32 -> bf16 (row-major [H1][FAN1] preserved; acts as B^T for the GEMM)
// ---------------------------------------------------------------------------
__global__ __launch_bounds__(256) void k_f32_to_bf16x4(
    const float* __restrict__ in, unsigned short* __restrict__ o, int n4)
{
    int i = blockIdx.x * 256 + threadIdx.x;
    if (i < n4) {
        float4 v = ((const float4*)in)[i];
        ushort4 r;
        r.x = f2bf(v.x); r.y = f2bf(v.y); r.z = f2bf(v.z); r.w = f2bf(v.w);
        ((ushort4*)o)[i] = r;
    }
}

// ---------------------------------------------------------------------------
// GEMM1 (split-K): P[ks][m][h] = sum_{k in half ks} xx[m][k]*W1[h][k]
// M=4096 N=1024 K=4608, bf16 MFMA 16x16x32.
// m97-proven geometry: BM=BN=128, BK=64, 4 waves (2x2), wave tile 64x64,
// 4x4 fragments -> 32 MFMA / 8 gl_lds per wave per K-step (2x the density
// of the previous 128x64 tile). Split-K=2 -> grid 512 = 2 blocks/CU for
// implicit cross-block overlap (m114). Bias/ReLU deferred to k_gemm2.
// XCD swizzle: wk = (bid&7)*64 + (bid>>3); each XCD gets 64 contiguous
// work items = one ks half x 8 bm x all 8 bn (A/B panel reuse in its L2).
// LDS chunk swizzle (both-sides involution): slot s of row r holds global
// chunk s ^ (r&7); gl_lds dest linear, per-lane GLOBAL source permuted;
// fragment reads apply the same XOR -> balanced banks.
// ---------------------------------------------------------------------------
__global__ __launch_bounds__(256, 2) void k_gemm1(
    const unsigned short* __restrict__ A,   // xx bf16 [4096][4608]
    const unsigned short* __restrict__ W,   // W1 bf16 [1024][4608]
    float* __restrict__ P)                  // [2][4096][1024] f32 partials
{
    constexpr int BM = 128, BN = 128, BK = 64;
    constexpr int K = KDIM;
    __shared__ unsigned short lA[BM * BK];  // 16 KB
    __shared__ unsigned short lB[BN * BK];  // 16 KB

    const int tid = threadIdx.x, lane = tid & 63, wave = tid >> 6;
    const int bid = blockIdx.x;
    const int wk  = (bid & 7) * 64 + (bid >> 3);   // XCD-grouped work id
    const int ks  = wk >> 8;                       // K-half 0/1
    const int rem = wk & 255;
    const int bm  = rem >> 3, bn = rem & 7;
    const int wm = wave >> 1, wn = wave & 1;
    const int k0 = ks * KHALF;

    // ---- staging setup: 1024 chunks per side, 4 per thread (j=0..3) ----
    // q = j*256 + tid; row = j*32 + wave*8 + (lane>>3); slot = lane&7;
    // swizzled global chunk sc = (lane&7) ^ (lane>>3)   [row&7 == lane>>3]
    const int rowq = wave * 8 + (lane >> 3);
    const int sc   = (lane & 7) ^ (lane >> 3);
    const unsigned short* gA[4];
    const unsigned short* gB[4];
    #pragma unroll
    for (int j = 0; j < 4; ++j) {
        gA[j] = A + (size_t)(bm * BM + j * 32 + rowq) * K + k0 + sc * 8;
        gB[j] = W + (size_t)(bn * BN + j * 32 + rowq) * K + k0 + sc * 8;
    }
    unsigned short* lAd[4];
    unsigned short* lBd[4];
    #pragma unroll
    for (int j = 0; j < 4; ++j) {
        lAd[j] = &lA[(j * 256 + wave * 64) * 8];
        lBd[j] = &lB[(j * 256 + wave * 64) * 8];
    }

    // ---- fragment read setup (swizzled) ----
    const int r16 = lane & 15;
    const int p0  = (lane >> 4) ^ (r16 & 7);   // slot for k-half 0 of BK
    const int p1  = p0 ^ 4;                    // slot for k-half 1 of BK
    const unsigned short* paBase = &lA[(wm * 64 + r16) * BK];
    const unsigned short* pbBase = &lB[(wn * 64 + r16) * BK];

    f32x4 acc[4][4];
    #pragma unroll
    for (int m = 0; m < 4; ++m)
        #pragma unroll
        for (int n = 0; n < 4; ++n) acc[m][n] = {0.f, 0.f, 0.f, 0.f};

    for (int kt = 0; kt < KHALF / BK; ++kt) {
        #pragma unroll
        for (int j = 0; j < 4; ++j) { gl_lds16(gA[j], lAd[j]); gA[j] += BK; }
        #pragma unroll
        for (int j = 0; j < 4; ++j) { gl_lds16(gB[j], lBd[j]); gB[j] += BK; }
        __syncthreads();   // vmcnt(0) drain; hidden by co-resident block

        bf16x8 fa[4][2], fb[4][2];
        #pragma unroll
        for (int m = 0; m < 4; ++m) {
            fa[m][0] = *(const bf16x8*)(paBase + m * 16 * BK + p0 * 8);
            fa[m][1] = *(const bf16x8*)(paBase + m * 16 * BK + p1 * 8);
        }
        #pragma unroll
        for (int n = 0; n < 4; ++n) {
            fb[n][0] = *(const bf16x8*)(pbBase + n * 16 * BK + p0 * 8);
            fb[n][1] = *(const bf16x8*)(pbBase + n * 16 * BK + p1 * 8);
        }
        #pragma unroll
        for (int h = 0; h < 2; ++h)
            #pragma unroll
            for (int m = 0; m < 4; ++m)
                #pragma unroll
                for (int n = 0; n < 4; ++n)
                    acc[m][n] = __builtin_amdgcn_mfma_f32_16x16x32_bf16(
                        fa[m][h], fb[n][h], acc[m][n], 0, 0, 0);
        __syncthreads();
    }

    // epilogue: C/D layout col=lane&15, row=(lane>>4)*4+reg; raw partials
    float* Pk = P + (size_t)ks * B_N * H1DIM;
    const int colbase = bn * BN + wn * 64 + r16;
    const int rowbase = bm * BM + wm * 64 + (lane >> 4) * 4;
    #pragma unroll
    for (int n = 0; n < 4; ++n) {
        const int col = colbase + n * 16;
        #pragma unroll
        for (int m = 0; m < 4; ++m) {
            const int row = rowbase + m * 16;
            #pragma unroll
            for (int j = 0; j < 4; ++j)
                Pk[(size_t)(row + j) * H1DIM + col] = acc[m][n][j];
        }
    }
}

// ---------------------------------------------------------------------------
// GEMM2 (+ fused split-K reduce, bias, relu):
// h[b][:] = relu(P0[b]+P1[b]+b1); out[b][c] = <h, W2[c]> + b2[c].
// One wave per batch row; W2 (16 KB) + b1 (4 KB) staged in LDS.
// ---------------------------------------------------------------------------
__global__ __launch_bounds__(256) void k_gemm2(
    const float* __restrict__ P, const float* __restrict__ W2,
    const float* __restrict__ b1, const float* __restrict__ b2,
    float* __restrict__ out)
{
    __shared__ float w2s[NCLS * H1DIM + H1DIM];
    const int tid = threadIdx.x, lane = tid & 63, wave = tid >> 6;
    const int row = blockIdx.x * 4 + wave;
    for (int i = tid; i < NCLS * H1DIM; i += 256) w2s[i] = W2[i];
    for (int i = tid; i < H1DIM; i += 256) w2s[NCLS * H1DIM + i] = b1[i];
    __syncthreads();

    const float4* p0 = (const float4*)(P + (size_t)row * H1DIM);
    const float4* p1 = (const float4*)(P + (size_t)(B_N + row) * H1DIM);
    const float4* w0 = (const float4*)&w2s[0];
    const float4* w1 = (const float4*)&w2s[H1DIM];
    const float4* w2 = (const float4*)&w2s[2 * H1DIM];
    const float4* w3 = (const float4*)&w2s[3 * H1DIM];
    const float4* bb = (const float4*)&w2s[4 * H1DIM];
    float a0 = 0.f, a1 = 0.f, a2 = 0.f, a3 = 0.f;
    #pragma unroll
    for (int j = 0; j < 4; ++j) {
        const int idx = j * 64 + lane;
        float4 x0 = p0[idx], x1 = p1[idx], bv = bb[idx];
        float4 h;
        h.x = x0.x + x1.x + bv.x; h.x = h.x > 0.f ? h.x : 0.f;
        h.y = x0.y + x1.y + bv.y; h.y = h.y > 0.f ? h.y : 0.f;
        h.z = x0.z + x1.z + bv.z; h.z = h.z > 0.f ? h.z : 0.f;
        h.w = x0.w + x1.w + bv.w; h.w = h.w > 0.f ? h.w : 0.f;
        float4 xv;
        xv = w0[idx]; a0 += h.x*xv.x + h.y*xv.y + h.z*xv.z + h.w*xv.w;
        xv = w1[idx]; a1 += h.x*xv.x + h.y*xv.y + h.z*xv.z + h.w*xv.w;
        xv = w2[idx]; a2 += h.x*xv.x + h.y*xv.y + h.z*xv.z + h.w*xv.w;
        xv = w3[idx]; a3 += h.x*xv.x + h.y*xv.y + h.z*xv.z + h.w*xv.w;
    }
    #pragma unroll
    for (int off = 32; off; off >>= 1) {
        a0 += __shfl_xor(a0, off);
        a1 += __shfl_xor(a1, off);
        a2 += __shfl_xor(a2, off);
        a3 += __shfl_xor(a3, off);
    }
    if (lane == 0) {
        float* o = out + (size_t)row * NCLS;
        o[0] = a0 + b2[0]; o[1] = a1 + b2[1]; o[2] = a2 + b2[2]; o[3] = a3 + b2[3];
    }
}

// ---------------------------------------------------------------------------
// Workspace layout (bytes):
//   [0, 37748736)                 xx bf16          4096*4608*2
//   [37748736, 47185920)          W1 bf16          1024*4608*2
//   [47185920, 80740352)          P f32 partials   2*4096*1024*4
// ---------------------------------------------------------------------------
extern "C" void kernel_launch(void* const* d_in, const int* in_sizes, int n_in,
                              void* d_out, int out_size, void* d_ws, size_t ws_size,
                              hipStream_t stream)
{
    const float* sim_stance = (const float*)d_in[0];
    const float* nli_stance = (const float*)d_in[1];
    const float* sim_body   = (const float*)d_in[2];
    const float* nli_body   = (const float*)d_in[3];
    const float* W1 = (const float*)d_in[4];
    const float* b1 = (const float*)d_in[5];
    const float* W2 = (const float*)d_in[6];
    const float* b2 = (const float*)d_in[7];
    float* out = (float*)d_out;

    char* ws = (char*)d_ws;
    unsigned short* xx  = (unsigned short*)ws;
    unsigned short* w1b = (unsigned short*)(ws + 37748736u);
    float*          P   = (float*)(ws + 37748736u + 9437184u);

    k_f32_to_bf16x4<<<dim3(4608), dim3(256), 0, stream>>>(W1, w1b, 1179648);
    k_topk_gather<<<dim3(B_N), dim3(256), 0, stream>>>(sim_stance, sim_body,
                                                       nli_stance, nli_body, xx);
    k_gemm1<<<dim3(512), dim3(256), 0, stream>>>(xx, w1b, P);
    k_gemm2<<<dim3(1024), dim3(256), 0, stream>>>(P, W2, b1, b2, out);
}